// Round 5
// baseline (187.406 us; speedup 1.0000x reference)
//
#include <hip/hip_runtime.h>

// Problem constants (fixed by the reference setup_inputs)
#define N_PTS 8192   // points per batch
#define M_Q   2048   // query points per batch
#define C_F   64     // feature channels
#define NS    32     // nsample
#define B_SZ  8      // batch

// ---------------------------------------------------------------------------
// K1: prep.
//  blocks [0, 1024):   transpose feat (b,c,n) -> featT (b,n,c). 64x64 LDS
//                      tile, stride 65 (2-way bank = free).
//  blocks [1024, 1280): xyz4[b*N+n] = (x, y, z, p2sum). p2sum in the exact
//                      numpy f32 order ((x*x+y*y)+z*z), contract OFF — feeds
//                      the pinned d2 formula bit-for-bit.
// ---------------------------------------------------------------------------
__global__ __launch_bounds__(256) void prep_kernel(
    const float* __restrict__ feat, const float* __restrict__ xyz,
    float* __restrict__ featT, float4* __restrict__ xyz4)
{
#pragma clang fp contract(off)
    __shared__ float lds[C_F * 65];
    if (blockIdx.x < B_SZ * 128) {
        const int b  = blockIdx.x >> 7;        // 128 n-tiles per batch
        const int n0 = (blockIdx.x & 127) * 64;
        {
            const int c4 = threadIdx.x >> 6;   // 0..3
            const int nn = threadIdx.x & 63;
#pragma unroll
            for (int k = 0; k < 16; ++k) {
                const int c = k * 4 + c4;
                lds[c * 65 + nn] = feat[((size_t)b * C_F + c) * N_PTS + n0 + nn];
            }
        }
        __syncthreads();
        {
            const int n4 = threadIdx.x >> 6;   // 0..3
            const int c  = threadIdx.x & 63;
#pragma unroll
            for (int k = 0; k < 16; ++k) {
                const int nn = k * 4 + n4;
                featT[((size_t)b * N_PTS + n0 + nn) * C_F + c] = lds[c * 65 + nn];
            }
        }
    } else {
        const int i = (blockIdx.x - B_SZ * 128) * 256 + (int)threadIdx.x; // 0..B*N-1
        const float p0 = xyz[i * 3 + 0];
        const float p1 = xyz[i * 3 + 1];
        const float p2 = xyz[i * 3 + 2];
        const float s  = (p0 * p0 + p1 * p1) + p2 * p2;   // np.sum order, no fma
        xyz4[i] = make_float4(p0, p1, p2, s);
    }
}

// ---------------------------------------------------------------------------
// K2: fused ball-query + gather. Block = 256 threads = 4 waves = 4 queries.
//
// Scan (per wave): macro-chunks of 256 pts, software-pipelined 1 deep (next
// chunk's 4 dwordx4 loads issue before this chunk's ballot rounds), early
// exit at 32 hits. Indices -> LDS sidx (no global round-trip).
// NUMERICS (pinned, rounds 2-4 passed absmax=0): d2 = (q2 + p2sum) - 2*qp,
// partials left-to-right f32, contract OFF, bit-matching numpy.
//
// Gather (no LDS stage, v4): lane = (qslot, sample, j): j in 0..3 owns 16
// consecutive channels = one 64B line of featT[b,n,:] (4 float4 loads).
// Direct scalar stores: per wave-store-inst, 4 rows x 16 consecutive samples
// = four full 64B lines (128B-aligned) -> zero write amplification, zero LDS
// traffic, 1 barrier/block (was 9).
// ---------------------------------------------------------------------------
__global__ __launch_bounds__(256) void qbg_kernel(
    const float4* __restrict__ xyz4, const float* __restrict__ nxyz,
    const float* __restrict__ featT, float* __restrict__ out)
{
#pragma clang fp contract(off)
    __shared__ int sidx[4][NS];

    const int lane = threadIdx.x & 63;
    const int w    = threadIdx.x >> 6;            // wave id 0..3
    const int q    = blockIdx.x * 4 + w;          // this wave's query
    const int b    = q >> 11;                     // M_Q = 2048
    const float4* __restrict__ xb = xyz4 + (size_t)b * N_PTS;

    // ---- scan phase ----
    {
        const float* __restrict__ qp = nxyz + (size_t)q * 3;
        const float qx = qp[0], qy = qp[1], qz = qp[2];
        const float q2 = (qx * qx + qy * qy) + qz * qz;   // np.sum order

        int  cnt = 0;
        int  first_idx = 0;
        bool have_first = false;

        float4 P[4], Pn[4];
#pragma unroll
        for (int cc = 0; cc < 4; ++cc) P[cc] = xb[cc * 64 + lane];

        for (int base = 0; base < N_PTS && cnt < NS; base += 256) {
            const int nb = base + 256;
            if (nb < N_PTS) {                      // prefetch next macro-chunk
#pragma unroll
                for (int cc = 0; cc < 4; ++cc) Pn[cc] = xb[nb + cc * 64 + lane];
            }
#pragma unroll
            for (int cc = 0; cc < 4; ++cc) {
                if (cnt >= NS) break;              // wave-uniform
                const float qpdot = (qx * P[cc].x + qy * P[cc].y) + qz * P[cc].z;
                const float d2 = (q2 + P[cc].w) - 2.0f * qpdot;   // ref formula
                const bool pred = d2 < 1.0f;
                const unsigned long long mask = __ballot(pred);
                if (mask) {
                    if (!have_first) {
                        first_idx = base + cc * 64 + __ffsll(mask) - 1;
                        have_first = true;
                    }
                    if (pred) {
                        const int pos = cnt + (int)__popcll(mask & ((1ull << lane) - 1ull));
                        if (pos < NS) sidx[w][pos] = base + cc * 64 + lane;
                    }
                    cnt += (int)__popcll(mask);
                }
            }
#pragma unroll
            for (int cc = 0; cc < 4; ++cc) P[cc] = Pn[cc];
        }
        if (cnt < NS) {
            for (int p = cnt + lane; p < NS; p += 64) sidx[w][p] = first_idx;
        }
    }
    __syncthreads();

    // ---- gather phase: direct stores, no LDS stage ----
    const int j  = threadIdx.x & 3;               // channel-quarter (16 ch)
    const int s  = (threadIdx.x >> 2) & 31;       // sample 0..31
    const int qs = threadIdx.x >> 7;              // query slot 0..1
    const size_t cstride = (size_t)M_Q * NS;      // 65536

    for (int g = 0; g < 2; ++g) {
        const int widx = g * 2 + qs;              // which wave's sidx
        const int qq   = blockIdx.x * 4 + widx;
        const int mm   = qq & (M_Q - 1);
        const int n    = sidx[widx][s];

        const float* __restrict__ fb =
            featT + ((size_t)b * N_PTS + n) * C_F + j * 16;   // one 64B line
        const float4 v0 = ((const float4*)fb)[0];
        const float4 v1 = ((const float4*)fb)[1];
        const float4 v2 = ((const float4*)fb)[2];
        const float4 v3 = ((const float4*)fb)[3];
        const float f[16] = { v0.x, v0.y, v0.z, v0.w,  v1.x, v1.y, v1.z, v1.w,
                              v2.x, v2.y, v2.z, v2.w,  v3.x, v3.y, v3.z, v3.w };

        const size_t obase = ((size_t)b * 67 * M_Q + mm) * NS + s;
        float* __restrict__ op = out + obase + (size_t)(3 + j * 16) * cstride;
#pragma unroll
        for (int i = 0; i < 16; ++i)
            op[(size_t)i * cstride] = f[i];       // 4 rows x 16 samples = 4 full lines/inst

        if (j == 0) {                             // xyz-diff rows 0..2
            const float4 pv = xb[n];
            const float* __restrict__ qp2 = nxyz + (size_t)qq * 3;
            float* __restrict__ ox = out + obase;
            ox[0]           = pv.x - qp2[0];
            ox[cstride]     = pv.y - qp2[1];
            ox[2 * cstride] = pv.z - qp2[2];
        }
    }
}

extern "C" void kernel_launch(void* const* d_in, const int* in_sizes, int n_in,
                              void* d_out, int out_size, void* d_ws, size_t ws_size,
                              hipStream_t stream)
{
    const float* xyz  = (const float*)d_in[0];   // (B, N, 3)
    const float* nxyz = (const float*)d_in[1];   // (B, M, 3)
    const float* feat = (const float*)d_in[2];   // (B, C, N)
    float* out = (float*)d_out;                  // (B, 67, M, 32)

    float*  featT = (float*)d_ws;                             // 16.8 MB
    float4* xyz4  = (float4*)((char*)d_ws + (20 << 20));      // 1 MB

    const int Q = B_SZ * M_Q;                    // 16384 queries

    prep_kernel<<<B_SZ * 128 + (B_SZ * N_PTS) / 256, 256, 0, stream>>>(
        feat, xyz, featT, xyz4);
    qbg_kernel<<<Q / 4, 256, 0, stream>>>(xyz4, nxyz, featT, out);
}

// Round 6
// 184.319 us; speedup vs baseline: 1.0168x; 1.0168x over previous
//
#include <hip/hip_runtime.h>

// Problem constants (fixed by the reference setup_inputs)
#define N_PTS 8192   // points per batch
#define M_Q   2048   // query points per batch
#define C_F   64     // feature channels
#define NS    32     // nsample
#define B_SZ  8      // batch

// ---------------------------------------------------------------------------
// K1: prep (unchanged from round 4, known-good).
//  blocks [0, 1024):   transpose feat (b,c,n) -> featT (b,n,c). 64x64 LDS
//                      tile, stride 65 (2-way bank = free).
//  blocks [1024, 1280): xyz4[b*N+n] = (x, y, z, p2sum), numpy f32 order,
//                      contract OFF — feeds the pinned d2 formula bit-for-bit.
// ---------------------------------------------------------------------------
__global__ __launch_bounds__(256) void prep_kernel(
    const float* __restrict__ feat, const float* __restrict__ xyz,
    float* __restrict__ featT, float4* __restrict__ xyz4)
{
#pragma clang fp contract(off)
    __shared__ float lds[C_F * 65];
    if (blockIdx.x < B_SZ * 128) {
        const int b  = blockIdx.x >> 7;        // 128 n-tiles per batch
        const int n0 = (blockIdx.x & 127) * 64;
        {
            const int c4 = threadIdx.x >> 6;   // 0..3
            const int nn = threadIdx.x & 63;
#pragma unroll
            for (int k = 0; k < 16; ++k) {
                const int c = k * 4 + c4;
                lds[c * 65 + nn] = feat[((size_t)b * C_F + c) * N_PTS + n0 + nn];
            }
        }
        __syncthreads();
        {
            const int n4 = threadIdx.x >> 6;   // 0..3
            const int c  = threadIdx.x & 63;
#pragma unroll
            for (int k = 0; k < 16; ++k) {
                const int nn = k * 4 + n4;
                featT[((size_t)b * N_PTS + n0 + nn) * C_F + c] = lds[c * 65 + nn];
            }
        }
    } else {
        const int i = (blockIdx.x - B_SZ * 128) * 256 + (int)threadIdx.x; // 0..B*N-1
        const float p0 = xyz[i * 3 + 0];
        const float p1 = xyz[i * 3 + 1];
        const float p2 = xyz[i * 3 + 2];
        const float s  = (p0 * p0 + p1 * p1) + p2 * p2;   // np.sum order, no fma
        xyz4[i] = make_float4(p0, p1, p2, s);
    }
}

// ---------------------------------------------------------------------------
// K2: fused ball-query + gather. Block = 256 threads = 4 waves = 4 queries.
//
// Scan (EXACT round-4 code, 178.5us best): macro-chunks of 256 pts, 4
// dwordx4 loads up front, 4 ballot/compact rounds, early exit at 32 hits.
// NUMERICS (pinned, rounds 2-5 passed absmax=0): d2 = (q2 + p2sum) - 2*qp,
// partials left-to-right f32, contract OFF, bit-matching numpy.
//
// Gather v5 (register transpose — replaces round-4's LDS stage):
// thread = (half, s4, c4): loads channels [c4*4..+3] for 4 samples
// (4 scattered dwordx4; per wave-inst 4 full 256B featT rows, amp 1.0),
// transposes 4x4 in registers, stores 4 sample-contiguous float4
// (16B-aligned; full-line writes). c4<3 lanes also emit xyz-diff rows.
// Zero LDS staging, zero extra barriers, ~40 VGPRs.
// ---------------------------------------------------------------------------
__global__ __launch_bounds__(256) void qbg_kernel(
    const float4* __restrict__ xyz4, const float* __restrict__ nxyz,
    const float* __restrict__ featT, float* __restrict__ out)
{
#pragma clang fp contract(off)
    __shared__ int sidx[4][NS];

    const int lane = threadIdx.x & 63;
    const int w    = threadIdx.x >> 6;            // wave id 0..3
    const int q    = blockIdx.x * 4 + w;          // this wave's query
    const int b    = q >> 11;                     // M_Q = 2048
    const float4* __restrict__ xb = xyz4 + (size_t)b * N_PTS;

    // ---- scan phase (round-4 exact) ----
    {
        const float* __restrict__ qp = nxyz + (size_t)q * 3;
        const float qx = qp[0], qy = qp[1], qz = qp[2];
        const float q2 = (qx * qx + qy * qy) + qz * qz;   // np.sum order

        int  cnt = 0;
        int  first_idx = 0;
        bool have_first = false;

        for (int base = 0; base < N_PTS && cnt < NS; base += 256) {
            float4 P[4];
#pragma unroll
            for (int cc = 0; cc < 4; ++cc)
                P[cc] = xb[base + cc * 64 + lane];
#pragma unroll
            for (int cc = 0; cc < 4; ++cc) {
                if (cnt >= NS) break;                       // wave-uniform
                const float qpdot = (qx * P[cc].x + qy * P[cc].y) + qz * P[cc].z;
                const float d2 = (q2 + P[cc].w) - 2.0f * qpdot;   // ref formula
                const bool pred = d2 < 1.0f;
                const unsigned long long mask = __ballot(pred);
                if (mask) {
                    if (!have_first) {
                        first_idx = base + cc * 64 + __ffsll(mask) - 1;
                        have_first = true;
                    }
                    if (pred) {
                        const int pos = cnt + (int)__popcll(mask & ((1ull << lane) - 1ull));
                        if (pos < NS) sidx[w][pos] = base + cc * 64 + lane;
                    }
                    cnt += (int)__popcll(mask);
                }
            }
        }
        if (cnt < NS) {
            for (int p = cnt + lane; p < NS; p += 64) sidx[w][p] = first_idx;
        }
    }
    __syncthreads();

    // ---- gather phase: register-transpose, direct float4 stores ----
    const int half = threadIdx.x >> 7;            // 0..1 (which query of pair)
    const int hid  = threadIdx.x & 127;
    const int c4   = hid & 15;                    // channel-quad 0..15
    const int s4   = hid >> 4;                    // sample-group 0..7
    const size_t cstride = (size_t)M_Q * NS;      // 65536

    const float4* __restrict__ fT =
        (const float4*)(featT + (size_t)b * N_PTS * C_F);  // 16 float4 per point

    for (int g = 0; g < 2; ++g) {
        const int widx = g * 2 + half;            // which wave's sidx
        const int qq   = blockIdx.x * 4 + widx;
        const int mm   = qq & (M_Q - 1);

        const int n0 = sidx[widx][s4 * 4 + 0];
        const int n1 = sidx[widx][s4 * 4 + 1];
        const int n2 = sidx[widx][s4 * 4 + 2];
        const int n3 = sidx[widx][s4 * 4 + 3];

        const float4 L0 = fT[(size_t)n0 * 16 + c4];
        const float4 L1 = fT[(size_t)n1 * 16 + c4];
        const float4 L2 = fT[(size_t)n2 * 16 + c4];
        const float4 L3 = fT[(size_t)n3 * 16 + c4];

        const size_t obase = ((size_t)b * 67 * M_Q + mm) * NS + s4 * 4;
        float* __restrict__ op = out + obase + (size_t)(3 + c4 * 4) * cstride;
        *(float4*)(op + 0 * cstride) = make_float4(L0.x, L1.x, L2.x, L3.x);
        *(float4*)(op + 1 * cstride) = make_float4(L0.y, L1.y, L2.y, L3.y);
        *(float4*)(op + 2 * cstride) = make_float4(L0.z, L1.z, L2.z, L3.z);
        *(float4*)(op + 3 * cstride) = make_float4(L0.w, L1.w, L2.w, L3.w);

        if (c4 < 3) {                             // xyz-diff rows 0..2
            const float qc = nxyz[qq * 3 + c4];
            const float* __restrict__ xf = (const float*)xb;
            float4 v;
            v.x = xf[n0 * 4 + c4] - qc;
            v.y = xf[n1 * 4 + c4] - qc;
            v.z = xf[n2 * 4 + c4] - qc;
            v.w = xf[n3 * 4 + c4] - qc;
            *(float4*)(out + obase + (size_t)c4 * cstride) = v;
        }
    }
}

extern "C" void kernel_launch(void* const* d_in, const int* in_sizes, int n_in,
                              void* d_out, int out_size, void* d_ws, size_t ws_size,
                              hipStream_t stream)
{
    const float* xyz  = (const float*)d_in[0];   // (B, N, 3)
    const float* nxyz = (const float*)d_in[1];   // (B, M, 3)
    const float* feat = (const float*)d_in[2];   // (B, C, N)
    float* out = (float*)d_out;                  // (B, 67, M, 32)

    float*  featT = (float*)d_ws;                             // 16.8 MB
    float4* xyz4  = (float4*)((char*)d_ws + (20 << 20));      // 1 MB

    const int Q = B_SZ * M_Q;                    // 16384 queries

    prep_kernel<<<B_SZ * 128 + (B_SZ * N_PTS) / 256, 256, 0, stream>>>(
        feat, xyz, featT, xyz4);
    qbg_kernel<<<Q / 4, 256, 0, stream>>>(xyz4, nxyz, featT, out);
}